// Round 5
// baseline (552.898 us; speedup 1.0000x reference)
//
#include <hip/hip_runtime.h>
#include <math.h>

#ifndef M_PI
#define M_PI 3.14159265358979323846
#endif

// Actual nodes_num is 336. BLOCK >= nodes_num, multiple of 64.
constexpr int MAXN  = 512;
constexpr int BLOCK = 384;          // 6 waves/block, one node per thread

__global__ __launch_bounds__(BLOCK)
void dynamicor_kernel(const int* __restrict__ batch,
                      const float* __restrict__ coords,
                      const float* __restrict__ fields,
                      const float* __restrict__ design,
                      const int* __restrict__ p_num_case,
                      const int* __restrict__ p_nodes_num,
                      float* __restrict__ out,
                      int total)
{
    const int c  = blockIdx.x;
    const int t  = threadIdx.x;
    const int ncase = *p_num_case;
    const int nn    = *p_nodes_num;     // 336

    __shared__ float s_n0x[MAXN], s_n0y[MAXN], s_pt[MAXN];
    __shared__ float s_n1x[MAXN], s_n1y[MAXN], s_utx[MAXN], s_uty[MAXN];
    __shared__ float s_red[4][BLOCK / 64];
    __shared__ int   s_off;

    // --- Speculative offset: batch = repeat(arange) is grouped, so
    // offsets[c] = c * (total/ncase). Verify with 2 broadcast loads ISSUED IN
    // PARALLEL with the data loads below; binary-search fallback (never taken
    // for this input) keeps any sorted grouped batch correct. This avoids
    // reading the 64 MB batch array (a real bincount would double traffic).
    const long long guess = (long long)c * (long long)(total / ncase);
    bool ok = (guess < (long long)total);
    const int b0 = ok ? batch[guess] : 0;                      // broadcast load
    const int bm = (ok && guess > 0) ? batch[guess - 1] : -1;  // broadcast load
    int off = (int)guess;

    // --- Speculative data loads (one node per thread, all independent).
    const bool active = (t < nn);
    float2 p0 = {0.f, 0.f}, p1 = {0.f, 0.f}, ut = {0.f, 0.f};
    float  pt = 0.f, a3 = 0.f, a4 = 0.f;
    if (active) {
        size_t i0 = (size_t)(off + t);
        size_t i1 = i0 + (size_t)nn;
        p0 = *(const float2*)(coords + 2 * i0);
        p1 = *(const float2*)(coords + 2 * i1);
        pt = fields[4 * i0];                          // f0[...,0]
        ut = *(const float2*)(fields + 4 * i1 + 2);   // f1[...,2:4], 8B-aligned
        a3 = design[5 * i0 + 3];
        a4 = design[5 * i0 + 4];
    }

    ok = ok && (b0 >= c) && (bm < c);
    if (!ok) {                       // block-uniform; never taken for this input
        if (t == 0) {
            long long lo = 0, hi = total;
            while (lo < hi) {
                long long mid = (lo + hi) >> 1;
                if (batch[mid] < c) lo = mid + 1; else hi = mid;
            }
            s_off = (int)lo;
        }
        __syncthreads();
        off = s_off;
        if (active) {
            size_t i0 = (size_t)(off + t);
            size_t i1 = i0 + (size_t)nn;
            p0 = *(const float2*)(coords + 2 * i0);
            p1 = *(const float2*)(coords + 2 * i1);
            pt = fields[4 * i0];
            ut = *(const float2*)(fields + 4 * i1 + 2);
            a3 = design[5 * i0 + 3];
            a4 = design[5 * i0 + 4];
        }
    }

    if (active) {
        s_n0x[t] = p0.x;  s_n0y[t] = p0.y;
        s_n1x[t] = p1.x;  s_n1y[t] = p1.y;
        s_pt[t]  = pt;
        s_utx[t] = ut.x;  s_uty[t] = ut.y;
    }
    __syncthreads();

    // --- Compute. Norm cancellations (N_norm == T_norm bitwise):
    //   Px = pt*T.y, Py = -pt*T.x, Tx_term = 50*tau_ave*T.x, Ty_term = 50*tau_ave*T.y
    // tau(k) recomputed at k=j and k=j+1 (cheap VALU; saves a barrier+array).
    auto tau_at = [&](int k) -> float {
        int kn = (k + 1 == nn) ? 0 : k + 1;
        float n0x = s_n0x[k], n0y = s_n0y[k];
        float Tx = s_n0x[kn] - n0x;
        float Ty = s_n0y[kn] - n0y;
        float Tnorm = sqrtf(Tx * Tx + Ty * Ty);
        float du = (s_utx[k] * Tx + s_uty[k] * Ty) / Tnorm;
        float dx = s_n1x[k] - n0x, dy = s_n1y[k] - n0y;
        float delta = sqrtf(dx * dx + dy * dy);
        return 1.9e-05f * du / delta;
    };

    float fx = 0.f, fy = 0.f;
    if (active) {
        int jn = (t + 1 == nn) ? 0 : t + 1;
        float Tx = s_n0x[jn] - s_n0x[t];
        float Ty = s_n0y[jn] - s_n0y[t];
        float p  = s_pt[t];
        float ta = 0.5f * (tau_at(t) + tau_at(jn));
        fx = -p * Ty + 50.f * ta * Tx;
        fy =  p * Tx + 50.f * ta * Ty;
    }

    // --- Reduction: 64-lane butterfly, then cross-wave via LDS.
    float d3 = a3, d4 = a4;
    for (int d = 32; d > 0; d >>= 1) {
        fx += __shfl_xor(fx, d);
        fy += __shfl_xor(fy, d);
        d3 += __shfl_xor(d3, d);
        d4 += __shfl_xor(d4, d);
    }
    const int w = t >> 6;
    if ((t & 63) == 0) {
        s_red[0][w] = fx;  s_red[1][w] = fy;
        s_red[2][w] = d3;  s_red[3][w] = d4;
    }
    __syncthreads();

    if (t == 0) {
        float FX = 0.f, FY = 0.f, D3 = 0.f, D4 = 0.f;
        #pragma unroll
        for (int i = 0; i < BLOCK / 64; ++i) {
            FX += s_red[0][i];  FY += s_red[1][i];
            D3 += s_red[2][i];  D4 += s_red[3][i];
        }
        const float ACOUSTIC = (float)sqrt(1.4 * 287.0 * 300.0);
        const float ALPHA    = (float)(6.0 * M_PI / 180.0);
        float Ma = (D3 / (float)nn) * 0.3f + 0.3f;
        float af = (D4 / (float)nn) * ALPHA;
        float ca = cosf(af), sa = sinf(af);
        float Fxn = FX * ca + FY * sa;
        float Fyn = FY * ca - Fxn * sa;       // reference uses the NEW Fx here
        float vel = ACOUSTIC * Ma;
        float q   = 0.5f * 1.225f * vel * vel;
        float2 res = {Fxn / q, Fyn / q};
        *(float2*)(out + 2 * c) = res;
    }
}

extern "C" void kernel_launch(void* const* d_in, const int* in_sizes, int n_in,
                              void* d_out, int out_size, void* d_ws, size_t ws_size,
                              hipStream_t stream) {
    const int*   batch     = (const int*)d_in[0];
    const float* coords    = (const float*)d_in[1];
    const float* fields    = (const float*)d_in[2];
    const float* design    = (const float*)d_in[3];
    const int*   num_case  = (const int*)d_in[4];
    const int*   nodes_num = (const int*)d_in[5];
    float* out = (float*)d_out;

    const int total = in_sizes[0];     // NUM_CASE * NODES_PER_CASE
    const int grid  = out_size / 2;    // = num_case (output is (num_case, 2))

    dynamicor_kernel<<<grid, BLOCK, 0, stream>>>(batch, coords, fields, design,
                                                 num_case, nodes_num, out, total);
}